// Round 7
// baseline (79.393 us; speedup 1.0000x reference)
//
#include <hip/hip_runtime.h>
#include <stdint.h>

// Problem constants (B=2, H=8, N=2048, D=64, f32 in/out).
#define B_ 2
#define H_ 8
#define N_ 2048
#define D_ 64
#define BH_ (B_ * H_)
#define NROWS (BH_ * N_)      // 32768
#define TJ 128                // j-segment width
#define NSEG (N_ / TJ)        // 16
#define IT 128                // i-tile rows per block (4 waves x 32 rows)
#define NACT 136              // per-bh active (it,jt): sum_{it=0}^{15}(it+1)
#define NBLK (NACT * BH_)     // 2176 = 8 * 272  (XCD-swizzle friendly)
#define EPSF 8e-3f            // margin below which we re-resolve the row in f64
#define INFF __int_as_float(0x7f800000)

using u64 = unsigned long long;
using u32 = unsigned int;
typedef __attribute__((ext_vector_type(8))) short short8;   // 8 bf16
typedef __attribute__((ext_vector_type(4))) float f32x4;

// ---------------------------------------------------------------------------
// Prep: split k into bf16 hi/lo written directly in MFMA B-FRAGMENT layout:
// [jg = globalrow/16][h(2)][lane(64)][16B], so phase1 reads one fragment as
// a single coalesced 1KB global_load_dwordx4 (no LDS, no barriers).
// Writer thread (row r, 8-elem group kg): h = kg>>2, lane = (kg&3)*16+(r&15).
// Reader lane l then holds row jg*16+(l&15), k-idx (l>>4)*8+e — the B layout.
// Also ksq[r] and count zeroing. Numerics identical to rounds 3-6.
// ---------------------------------------------------------------------------
__global__ __launch_bounds__(256) void prep_k(
    const float* __restrict__ k, char* __restrict__ khi_g,
    char* __restrict__ klo_g, float* __restrict__ ksq_g,
    u32* __restrict__ count)
{
  if (blockIdx.x == 0 && threadIdx.x == 0) count[0] = 0;
  const int t = (int)blockIdx.x * 256 + threadIdx.x;  // NROWS*8 total
  const int r = t >> 3, kg = t & 7;
  const float* kp = k + (size_t)r * D_ + kg * 8;
  const float4 f0 = *(const float4*)kp;
  const float4 f1 = *(const float4*)(kp + 4);
  const float vv[8] = {f0.x, f0.y, f0.z, f0.w, f1.x, f1.y, f1.z, f1.w};
  u32 hw[4], lw[4];
  float ps = 0.f;
  #pragma unroll
  for (int e = 0; e < 4; ++e) {
    const float va = vv[2 * e], vb = vv[2 * e + 1];
    ps = fmaf(va, va, ps); ps = fmaf(vb, vb, ps);
    const u32 ha = __float_as_uint(va) & 0xFFFF0000u;
    const u32 hb = __float_as_uint(vb) & 0xFFFF0000u;
    hw[e] = (ha >> 16) | hb;
    const u32 la = __float_as_uint(va - __uint_as_float(ha));
    const u32 lb = __float_as_uint(vb - __uint_as_float(hb));
    lw[e] = (la >> 16) | (lb & 0xFFFF0000u);
  }
  const size_t off = ((size_t)(r >> 4) * 2 + (kg >> 2)) * 1024 +
                     (size_t)(((kg & 3) << 4) + (r & 15)) * 16;
  *(uint4*)(khi_g + off) = make_uint4(hw[0], hw[1], hw[2], hw[3]);
  *(uint4*)(klo_g + off) = make_uint4(lw[0], lw[1], lw[2], lw[3]);
  float ssum = ps;                                    // |k_row|^2
  ssum += __shfl_xor(ssum, 1);
  ssum += __shfl_xor(ssum, 2);
  ssum += __shfl_xor(ssum, 4);
  if (kg == 0) ksq_g[r] = ssum;
}

// ---------------------------------------------------------------------------
// Phase 1 (MFMA, no LDS, no barriers): per (row, j-segment) argmin of
// score = ksq_j - 2 q.k (qsq constant per row: cancels in argmin and EPSF
// margin). One (it,jt) tile per block; 4 independent waves own 32 rows each
// (2 A-frag sets). B-fragments read per 16-wide j-subtile as 4 coalesced 1KB
// loads from prep's fragment image (L2-resident, ~280MB aggregate at L2 BW).
// dot = hi*hi + hi*lo + lo*hi (split-bf16, err ~1e-4 << EPSF/2).
// Float best/sec/bj in-loop (ascending j per lane: strict < keeps first
// index); sortable-key u64 cross-lane reduce (u64-min == first-index
// tie-break, matching np.argmax).
// ---------------------------------------------------------------------------
__global__ __launch_bounds__(256, 5) void phase1(
    const float* __restrict__ q, const char* __restrict__ khi_g,
    const char* __restrict__ klo_g, const float* __restrict__ ksq_g,
    u64* __restrict__ bestseg, u32* __restrict__ secseg)
{
  const int b = (int)blockIdx.x;
  const int orig = (b & 7) * (NBLK / 8) + (b >> 3);   // XCD swizzle (bijective)
  const int bh = orig / NACT;
  const int x = orig - bh * NACT;
  int it = 0;
  while ((it + 1) * (it + 2) / 2 <= x) ++it;          // triangular decode
  const int jt = x - it * (it + 1) / 2;
  const int i0 = it * IT, j0 = jt * TJ;
  const bool diag = (jt == it);

  const int tid = threadIdx.x;
  const int lane = tid & 63, w = tid >> 6;
  const int g = lane >> 4, c0 = lane & 15;

  // ---- q: 2 A-frag sets (rows iminw+s*16+c0) converted in-kernel ----
  const int iminw = i0 + w * 32;
  short8 ah[2][2], al[2][2];
  #pragma unroll
  for (int s = 0; s < 2; ++s) {
    const float* qrow =
        q + ((size_t)bh * N_ + iminw + s * 16 + c0) * D_ + g * 8;
    #pragma unroll
    for (int h = 0; h < 2; ++h) {
      const float4 f0 = *(const float4*)(qrow + h * 32);
      const float4 f1 = *(const float4*)(qrow + h * 32 + 4);
      const float vv[8] = {f0.x, f0.y, f0.z, f0.w, f1.x, f1.y, f1.z, f1.w};
      #pragma unroll
      for (int e = 0; e < 8; ++e) {
        const float v = vv[e];
        const u32 hb = __float_as_uint(v) & 0xFFFF0000u;
        ah[s][h][e] = (short)(hb >> 16);
        al[s][h][e] = (short)(__float_as_uint(v - __uint_as_float(hb)) >> 16);
      }
    }
  }

  // ---- running best/sec over the segment ----
  float bf[2][4], sf[2][4];
  u32 bj[2][4];
  #pragma unroll
  for (int s = 0; s < 2; ++s)
    #pragma unroll
    for (int r2 = 0; r2 < 4; ++r2) {
      bf[s][r2] = INFF; sf[s][r2] = INFF; bj[s][r2] = 0;
    }

  const size_t fbase = ((size_t)bh * 128 + jt * 8) * 2048;  // 2KB per jg
  const int jsmax = diag ? (2 * w + 1) : 7;
  for (int js = 0; js <= jsmax; ++js) {
    const char* ph = khi_g + fbase + js * 2048 + lane * 16;
    const char* pl = klo_g + fbase + js * 2048 + lane * 16;
    const short8 kh0 = *(const short8*)(ph);
    const short8 kh1 = *(const short8*)(ph + 1024);
    const short8 kl0 = *(const short8*)(pl);
    const short8 kl1 = *(const short8*)(pl + 1024);
    const float ks = ksq_g[(size_t)bh * N_ + j0 + js * 16 + c0];
    const int jcol = j0 + js * 16 + c0;
    #pragma unroll
    for (int s = 0; s < 2; ++s) {
      if (diag && js > 2 * w + s) continue;       // above causal range
      const bool dsub = diag && (js == 2 * w + s);
      f32x4 aA = {0.f, 0.f, 0.f, 0.f}, aB = {0.f, 0.f, 0.f, 0.f};
      aA = __builtin_amdgcn_mfma_f32_16x16x32_bf16(ah[s][0], kh0, aA, 0, 0, 0);
      aB = __builtin_amdgcn_mfma_f32_16x16x32_bf16(ah[s][1], kh1, aB, 0, 0, 0);
      aA = __builtin_amdgcn_mfma_f32_16x16x32_bf16(ah[s][0], kl0, aA, 0, 0, 0);
      aB = __builtin_amdgcn_mfma_f32_16x16x32_bf16(ah[s][1], kl1, aB, 0, 0, 0);
      aA = __builtin_amdgcn_mfma_f32_16x16x32_bf16(al[s][0], kh0, aA, 0, 0, 0);
      aB = __builtin_amdgcn_mfma_f32_16x16x32_bf16(al[s][1], kh1, aB, 0, 0, 0);
      #pragma unroll
      for (int reg = 0; reg < 4; ++reg) {
        float score = fmaf(-2.f, aA[reg] + aB[reg], ks);
        if (dsub) {
          const int irow = iminw + s * 16 + g * 4 + reg;
          if (jcol > irow) score = INFF;
        }
        const float loser = fmaxf(bf[s][reg], score);
        sf[s][reg] = fminf(sf[s][reg], loser);
        if (score < bf[s][reg]) bj[s][reg] = (u32)jcol;
        bf[s][reg] = fminf(bf[s][reg], score);
      }
    }
  }

  // ---- cross-lane reduce over the 16 col-slots; store one entry/row ----
  #pragma unroll
  for (int s = 0; s < 2; ++s) {
    #pragma unroll
    for (int reg = 0; reg < 4; ++reg) {
      const u32 bbits = __float_as_uint(bf[s][reg]);
      const u32 key = bbits ^ (u32)(((int)bbits >> 31) | 0x80000000);
      u64 pk = ((u64)key << 32) | bj[s][reg];
      float bv = bf[s][reg], sv = sf[s][reg];
      #pragma unroll
      for (int m = 1; m < 16; m <<= 1) {
        const u64 opk = (u64)__shfl_xor((long long)pk, m);
        const float obv = __shfl_xor(bv, m);
        const float osv = __shfl_xor(sv, m);
        const bool take = opk < pk;
        const float loser = take ? bv : obv;
        sv = fminf(fminf(sv, osv), loser);
        if (take) { pk = opk; bv = obv; }
      }
      if (c0 == 0) {
        const size_t rr = (size_t)bh * N_ + iminw + s * 16 + g * 4 + reg;
        bestseg[(size_t)jt * NROWS + rr] = pk;
        secseg[(size_t)jt * NROWS + rr] = __float_as_uint(sv);
      }
    }
  }
}

// ---------------------------------------------------------------------------
// Combine + gather fused. Block = 256 thr handles 64 rows: stage A (t<64)
// reduces the row's <=16 segment entries (u64-min keeps first index; float
// recovered via inverse key transform), flags near-ties; stage B all 256
// threads gather v rows to out (float4). Flagged rows get provisional output
// here and are overwritten by exact_gather.
// ---------------------------------------------------------------------------
__global__ __launch_bounds__(256) void combine_gather(
    const u64* __restrict__ bestseg, const u32* __restrict__ secseg,
    const float* __restrict__ v, float* __restrict__ out,
    u32* __restrict__ flaglist, u32* __restrict__ count)
{
  __shared__ u32 idx_s[64];
  const int tid = threadIdx.x;
  const int r0 = (int)blockIdx.x * 64;
  if (tid < 64) {
    const int r = r0 + tid;
    const int i = r & (N_ - 1);
    const int smax = i >> 7;
    u64 b0 = ~0ull;
    float bcur = INFF, s1 = INFF;
    int sstar = 0;
    for (int s = 0; s <= smax; ++s) {
      const u64 kk = bestseg[(size_t)s * NROWS + r];
      const u32 key = (u32)(kk >> 32);
      const u32 bits = (key & 0x80000000u) ? (key ^ 0x80000000u) : ~key;
      const float f = __uint_as_float(bits);
      if (kk < b0) { s1 = fminf(s1, bcur); b0 = kk; bcur = f; sstar = s; }
      else s1 = fminf(s1, f);
    }
    s1 = fminf(s1, __uint_as_float(secseg[(size_t)sstar * NROWS + r]));
    idx_s[tid] = (u32)(b0 & 0xFFFFu);
    if (s1 - bcur < EPSF) {            // NaN-safe: INF-INF=NaN -> false
      const u32 p = atomicAdd(count, 1u);
      flaglist[p] = (u32)r;
    }
  }
  __syncthreads();
  #pragma unroll
  for (int iter = 0; iter < 4; ++iter) {
    const int task = tid + iter * 256;
    const int rl = task >> 4, cc = task & 15;
    const int r = r0 + rl;
    const u32 j = idx_s[rl];
    const int bh = r >> 11;
    const float4 val = ((const float4*)(v + ((size_t)bh * N_ + j) * D_))[cc];
    ((float4*)(out + (size_t)r * D_))[cc] = val;
  }
}

// ---------------------------------------------------------------------------
// Exact f64 re-resolution of near-tie rows (+ direct out write).
// ---------------------------------------------------------------------------
__global__ __launch_bounds__(256) void exact_gather(
    const float* __restrict__ q, const float* __restrict__ k,
    const float* __restrict__ v, float* __restrict__ out,
    const u32* __restrict__ flaglist, const u32* __restrict__ count)
{
  __shared__ double qd[D_];
  __shared__ double sd[256];
  __shared__ int sj[256];
  const int tid = threadIdx.x;
  const int cnt = (int)count[0];
  for (int li = blockIdx.x; li < cnt; li += (int)gridDim.x) {
    const int r = (int)flaglist[li];
    const int bh = r >> 11;
    const int i = r & (N_ - 1);
    const float* qr = q + (size_t)r * D_;
    const float* kb = k + (size_t)bh * N_ * D_;
    if (tid < D_) qd[tid] = (double)qr[tid];
    __syncthreads();
    double qsqd = 0.0;
    for (int d = 0; d < D_; ++d) qsqd = fma(qd[d], qd[d], qsqd);
    double bbest = 1e300;
    int bjj = 0;
    for (int j = tid; j <= i; j += 256) {
      const float* kr = kb + (size_t)j * D_;
      double a0 = 0, a1 = 0, s0 = 0, s1 = 0;
      for (int d = 0; d < D_; d += 2) {
        const double k0 = (double)kr[d], k1 = (double)kr[d + 1];
        a0 = fma(qd[d], k0, a0);  a1 = fma(qd[d + 1], k1, a1);
        s0 = fma(k0, k0, s0);     s1 = fma(k1, k1, s1);
      }
      const double raw = (qsqd + (s0 + s1)) - 2.0 * (a0 + a1);
      const double d2 = raw > 0.0 ? raw : 0.0;
      if (d2 < bbest) { bbest = d2; bjj = j; }   // ascending j -> first on tie
    }
    sd[tid] = bbest; sj[tid] = bjj;
    __syncthreads();
    for (int s = 128; s > 0; s >>= 1) {
      if (tid < s) {
        const double ob = sd[tid + s]; const int oj = sj[tid + s];
        if (ob < sd[tid] || (ob == sd[tid] && oj < sj[tid])) {
          sd[tid] = ob; sj[tid] = oj;
        }
      }
      __syncthreads();
    }
    const int jwin = sj[0];
    if (tid < 16) {
      const float4 val =
          ((const float4*)(v + ((size_t)bh * N_ + jwin) * D_))[tid];
      ((float4*)(out + (size_t)r * D_))[tid] = val;
    }
    __syncthreads();
  }
}

// ---------------------------------------------------------------------------
extern "C" void kernel_launch(void* const* d_in, const int* in_sizes, int n_in,
                              void* d_out, int out_size, void* d_ws,
                              size_t ws_size, hipStream_t stream) {
  const float* q = (const float*)d_in[0];
  const float* k = (const float*)d_in[1];
  const float* v = (const float*)d_in[2];
  float* out = (float*)d_out;

  // ws layout (256 MiB available):
  // [0: count][4K: flaglist 128K][256K: ksq 128K][1M: khi 4M][8M: klo 4M]
  // [16M: bestseg 4M][24M: secseg 2M]
  char* ws = (char*)d_ws;
  u32* count = (u32*)ws;
  u32* flaglist = (u32*)(ws + 4096);
  float* ksq_g = (float*)(ws + 256 * 1024);
  char* khi_g = ws + 1ull * 1024 * 1024;
  char* klo_g = ws + 8ull * 1024 * 1024;
  u64* bestseg = (u64*)(ws + 16ull * 1024 * 1024);
  u32* secseg = (u32*)(ws + 24ull * 1024 * 1024);

  prep_k<<<(NROWS * 8) / 256, 256, 0, stream>>>(k, khi_g, klo_g, ksq_g, count);
  phase1<<<NBLK, 256, 0, stream>>>(q, khi_g, klo_g, ksq_g, bestseg, secseg);
  combine_gather<<<NROWS / 64, 256, 0, stream>>>(bestseg, secseg, v, out,
                                                 flaglist, count);
  exact_gather<<<64, 256, 0, stream>>>(q, k, v, out, flaglist, count);
}

// Round 8
// 66.763 us; speedup vs baseline: 1.1892x; 1.1892x over previous
//
#include <hip/hip_runtime.h>
#include <stdint.h>

// Problem constants (B=2, H=8, N=2048, D=64, f32 in/out).
#define B_ 2
#define H_ 8
#define N_ 2048
#define D_ 64
#define BH_ (B_ * H_)
#define NROWS (BH_ * N_)      // 32768
#define TPB_ 288              // wave-tasks per bh: sum_{g2=0}^{63} ceil((2g2+2)/16)
#define NTASK (TPB_ * BH_)    // 4608
#define NBLK1 (NTASK / 4)     // 1152 = 8 * 144 (4 waves per block, XCD-swizzlable)
#define MAXCH 8               // max chunks per 32-row group
#define EPSF 8e-3f            // margin below which we re-resolve the row in f64
#define INFF __int_as_float(0x7f800000)

using u64 = unsigned long long;
using u32 = unsigned int;
typedef __attribute__((ext_vector_type(8))) short short8;   // 8 bf16
typedef __attribute__((ext_vector_type(4))) float f32x4;

// ---------------------------------------------------------------------------
// Prep (verbatim from round 7, passed): split k into bf16 hi/lo in MFMA
// B-FRAGMENT layout [jg][h(2)][lane(64)][16B] so phase1 reads one fragment as
// a single coalesced 1KB global_load_dwordx4. Writer thread (row r, group kg):
// h = kg>>2, lane = (kg&3)*16 + (r&15). Also ksq[r]; zeroes count.
// ---------------------------------------------------------------------------
__global__ __launch_bounds__(256) void prep_k(
    const float* __restrict__ k, char* __restrict__ khi_g,
    char* __restrict__ klo_g, float* __restrict__ ksq_g,
    u32* __restrict__ count)
{
  if (blockIdx.x == 0 && threadIdx.x == 0) count[0] = 0;
  const int t = (int)blockIdx.x * 256 + threadIdx.x;  // NROWS*8 total
  const int r = t >> 3, kg = t & 7;
  const float* kp = k + (size_t)r * D_ + kg * 8;
  const float4 f0 = *(const float4*)kp;
  const float4 f1 = *(const float4*)(kp + 4);
  const float vv[8] = {f0.x, f0.y, f0.z, f0.w, f1.x, f1.y, f1.z, f1.w};
  u32 hw[4], lw[4];
  float ps = 0.f;
  #pragma unroll
  for (int e = 0; e < 4; ++e) {
    const float va = vv[2 * e], vb = vv[2 * e + 1];
    ps = fmaf(va, va, ps); ps = fmaf(vb, vb, ps);
    const u32 ha = __float_as_uint(va) & 0xFFFF0000u;
    const u32 hb = __float_as_uint(vb) & 0xFFFF0000u;
    hw[e] = (ha >> 16) | hb;
    const u32 la = __float_as_uint(va - __uint_as_float(ha));
    const u32 lb = __float_as_uint(vb - __uint_as_float(hb));
    lw[e] = (la >> 16) | (lb & 0xFFFF0000u);
  }
  const size_t off = ((size_t)(r >> 4) * 2 + (kg >> 2)) * 1024 +
                     (size_t)(((kg & 3) << 4) + (r & 15)) * 16;
  *(uint4*)(khi_g + off) = make_uint4(hw[0], hw[1], hw[2], hw[3]);
  *(uint4*)(klo_g + off) = make_uint4(lw[0], lw[1], lw[2], lw[3]);
  float ssum = ps;                                    // |k_row|^2
  ssum += __shfl_xor(ssum, 1);
  ssum += __shfl_xor(ssum, 2);
  ssum += __shfl_xor(ssum, 4);
  if (kg == 0) ksq_g[r] = ssum;
}

// ---------------------------------------------------------------------------
// Phase 1: independent wave-tasks, no LDS, no barriers, explicit register
// double-buffer. Task = (bh, 32-row group g2, chunk c of <=16 j-subtiles).
// Per subtile: 4 coalesced 1KB B-fragment loads (prefetched one subtile
// ahead) + 12 MFMA (2 s-sets x {hi*hi, hi*lo, lo*hi} x 2 K-halves) + float
// best/sec/argmin tracking of score = ksq_j - 2 q.k (qsq constant per row:
// cancels in argmin and in the EPSF margin). Ascending j per lane + strict <
// keeps first index; sortable-key u64 cross-lane reduce over the 16 col-slots
// (u64-min == first-index tie-break, matching np.argmax).
// Blocks of 4 independent waves; XCD swizzle gives each XCD 2 bh (1MB frag
// working set, L2-resident).
// ---------------------------------------------------------------------------
__global__ __launch_bounds__(256, 4) void phase1(
    const float* __restrict__ q, const char* __restrict__ khi_g,
    const char* __restrict__ klo_g, const float* __restrict__ ksq_g,
    u64* __restrict__ bestc, u32* __restrict__ secc)
{
  const int b = (int)blockIdx.x;
  const int ob = (b & 7) * (NBLK1 / 8) + (b >> 3);    // XCD swizzle (bijective)
  const int task = ob * 4 + (threadIdx.x >> 6);
  const int bh = task / TPB_;
  int rem = task - bh * TPB_;
  int g2 = 0, nc = 1;                                 // nc(g2) = (2g2+17)>>4
  while (rem >= nc) { rem -= nc; ++g2; nc = (2 * g2 + 17) >> 4; }
  const int c = rem;
  const int jfirst = c * 16;
  const int jlast = min(jfirst + 15, 2 * g2 + 1);     // inclusive subtile idx

  const int lane = threadIdx.x & 63;
  const int grp = lane >> 4, c0 = lane & 15;
  const int i0 = g2 * 32;

  // ---- q: 2 A-frag sets (rows i0 + s*16 + c0), bf16 hi/lo, in-kernel ----
  short8 ah[2][2], al[2][2];
  #pragma unroll
  for (int s = 0; s < 2; ++s) {
    const float* qrow =
        q + ((size_t)bh * N_ + i0 + s * 16 + c0) * D_ + grp * 8;
    #pragma unroll
    for (int h = 0; h < 2; ++h) {
      const float4 f0 = *(const float4*)(qrow + h * 32);
      const float4 f1 = *(const float4*)(qrow + h * 32 + 4);
      const float vv[8] = {f0.x, f0.y, f0.z, f0.w, f1.x, f1.y, f1.z, f1.w};
      #pragma unroll
      for (int e = 0; e < 8; ++e) {
        const float v = vv[e];
        const u32 hb = __float_as_uint(v) & 0xFFFF0000u;
        ah[s][h][e] = (short)(hb >> 16);
        al[s][h][e] = (short)(__float_as_uint(v - __uint_as_float(hb)) >> 16);
      }
    }
  }

  // ---- main loop with one-subtile register prefetch ----
  float bf[2][4], sf[2][4];
  u32 bj[2][4];
  #pragma unroll
  for (int s = 0; s < 2; ++s)
    #pragma unroll
    for (int r2 = 0; r2 < 4; ++r2) {
      bf[s][r2] = INFF; sf[s][r2] = INFF; bj[s][r2] = 0;
    }

  const size_t fb = (size_t)bh * 128 * 2048;          // 256KB per bh
  const char* ph = khi_g + fb + (size_t)jfirst * 2048 + lane * 16;
  const char* pl = klo_g + fb + (size_t)jfirst * 2048 + lane * 16;
  const float* pk = ksq_g + (size_t)bh * N_ + jfirst * 16 + c0;

  short8 ch0 = *(const short8*)(ph);
  short8 ch1 = *(const short8*)(ph + 1024);
  short8 cl0 = *(const short8*)(pl);
  short8 cl1 = *(const short8*)(pl + 1024);
  float cks = *pk;

  for (int js = jfirst; js <= jlast; ++js) {
    // prefetch next subtile (redundant re-load of current on last iter)
    const int adv = (js < jlast) ? 1 : 0;
    const char* nh = ph + adv * 2048;
    const char* nl = pl + adv * 2048;
    const short8 nh0 = *(const short8*)(nh);
    const short8 nh1 = *(const short8*)(nh + 1024);
    const short8 nl0 = *(const short8*)(nl);
    const short8 nl1 = *(const short8*)(nl + 1024);
    const float nks = pk[adv * 16];
    ph = nh; pl = nl; pk += adv * 16;

    const int jcol = js * 16 + c0;
    #pragma unroll
    for (int s = 0; s < 2; ++s) {
      if (js > 2 * g2 + s) continue;                  // above causal range
      const bool dsub = (js == 2 * g2 + s);           // diagonal subtile
      f32x4 aA = {0.f, 0.f, 0.f, 0.f}, aB = {0.f, 0.f, 0.f, 0.f};
      aA = __builtin_amdgcn_mfma_f32_16x16x32_bf16(ah[s][0], ch0, aA, 0, 0, 0);
      aB = __builtin_amdgcn_mfma_f32_16x16x32_bf16(ah[s][1], ch1, aB, 0, 0, 0);
      aA = __builtin_amdgcn_mfma_f32_16x16x32_bf16(ah[s][0], cl0, aA, 0, 0, 0);
      aB = __builtin_amdgcn_mfma_f32_16x16x32_bf16(ah[s][1], cl1, aB, 0, 0, 0);
      aA = __builtin_amdgcn_mfma_f32_16x16x32_bf16(al[s][0], ch0, aA, 0, 0, 0);
      aB = __builtin_amdgcn_mfma_f32_16x16x32_bf16(al[s][1], ch1, aB, 0, 0, 0);
      #pragma unroll
      for (int reg = 0; reg < 4; ++reg) {
        float score = fmaf(-2.f, aA[reg] + aB[reg], cks);
        if (dsub) {
          const int irow = i0 + s * 16 + grp * 4 + reg;
          if (jcol > irow) score = INFF;
        }
        const float loser = fmaxf(bf[s][reg], score);
        sf[s][reg] = fminf(sf[s][reg], loser);
        if (score < bf[s][reg]) bj[s][reg] = (u32)jcol;
        bf[s][reg] = fminf(bf[s][reg], score);
      }
    }
    ch0 = nh0; ch1 = nh1; cl0 = nl0; cl1 = nl1; cks = nks;
  }

  // ---- cross-lane reduce over the 16 col-slots; store one entry/row ----
  #pragma unroll
  for (int s = 0; s < 2; ++s) {
    #pragma unroll
    for (int reg = 0; reg < 4; ++reg) {
      const u32 bbits = __float_as_uint(bf[s][reg]);
      const u32 key = bbits ^ (u32)(((int)bbits >> 31) | 0x80000000);
      u64 pkk = ((u64)key << 32) | bj[s][reg];
      float sv = sf[s][reg];
      #pragma unroll
      for (int m = 1; m < 16; m <<= 1) {
        const u64 opk = (u64)__shfl_xor((long long)pkk, m);
        const float osv = __shfl_xor(sv, m);
        // decode best values from keys (saves one shuffle)
        const u32 mk = (u32)(pkk >> 32), ok = (u32)(opk >> 32);
        const u32 lk = (opk < pkk) ? mk : ok;         // loser's key
        const u32 lb = (lk & 0x80000000u) ? (lk ^ 0x80000000u) : ~lk;
        sv = fminf(fminf(sv, osv), __uint_as_float(lb));
        if (opk < pkk) pkk = opk;
      }
      if (c0 == 0) {
        const size_t rr = (size_t)bh * N_ + i0 + s * 16 + grp * 4 + reg;
        bestc[(size_t)c * NROWS + rr] = pkk;
        secc[(size_t)c * NROWS + rr] = __float_as_uint(sv);
      }
    }
  }
}

// ---------------------------------------------------------------------------
// Combine + gather fused. Block = 256 thr handles 64 rows: stage A (t<64)
// reduces the row's <=8 chunk partials (u64-min keeps first index; best value
// decoded from sortable key), flags near-ties; stage B all 256 threads gather
// v rows to out (float4). Flagged rows get provisional output here and are
// overwritten by exact_gather.
// ---------------------------------------------------------------------------
__global__ __launch_bounds__(256) void combine_gather(
    const u64* __restrict__ bestc, const u32* __restrict__ secc,
    const float* __restrict__ v, float* __restrict__ out,
    u32* __restrict__ flaglist, u32* __restrict__ count)
{
  __shared__ u32 idx_s[64];
  const int tid = threadIdx.x;
  const int r0 = (int)blockIdx.x * 64;
  if (tid < 64) {
    const int r = r0 + tid;
    const int i = r & (N_ - 1);
    const int g2 = i >> 5;
    const int nch = (2 * g2 + 17) >> 4;    // chunks covering this 32-row group
    u64 b0 = ~0ull;
    float bcur = INFF, s1 = INFF;
    int cstar = 0;
    for (int c2 = 0; c2 < nch; ++c2) {
      const u64 kk = bestc[(size_t)c2 * NROWS + r];
      const u32 key = (u32)(kk >> 32);
      const u32 bits = (key & 0x80000000u) ? (key ^ 0x80000000u) : ~key;
      const float f = __uint_as_float(bits);
      if (kk < b0) { s1 = fminf(s1, bcur); b0 = kk; bcur = f; cstar = c2; }
      else s1 = fminf(s1, f);
    }
    s1 = fminf(s1, __uint_as_float(secc[(size_t)cstar * NROWS + r]));
    idx_s[tid] = (u32)(b0 & 0xFFFFu);
    if (s1 - bcur < EPSF) {            // NaN-safe: INF-INF=NaN -> false
      const u32 p = atomicAdd(count, 1u);
      flaglist[p] = (u32)r;
    }
  }
  __syncthreads();
  #pragma unroll
  for (int iter = 0; iter < 4; ++iter) {
    const int task = tid + iter * 256;
    const int rl = task >> 4, cc = task & 15;
    const int r = r0 + rl;
    const u32 j = idx_s[rl];
    const int bh = r >> 11;
    const float4 val = ((const float4*)(v + ((size_t)bh * N_ + j) * D_))[cc];
    ((float4*)(out + (size_t)r * D_))[cc] = val;
  }
}

// ---------------------------------------------------------------------------
// Exact f64 re-resolution of near-tie rows (+ direct out write).
// ---------------------------------------------------------------------------
__global__ __launch_bounds__(256) void exact_gather(
    const float* __restrict__ q, const float* __restrict__ k,
    const float* __restrict__ v, float* __restrict__ out,
    const u32* __restrict__ flaglist, const u32* __restrict__ count)
{
  __shared__ double qd[D_];
  __shared__ double sd[256];
  __shared__ int sj[256];
  const int tid = threadIdx.x;
  const int cnt = (int)count[0];
  for (int li = blockIdx.x; li < cnt; li += (int)gridDim.x) {
    const int r = (int)flaglist[li];
    const int bh = r >> 11;
    const int i = r & (N_ - 1);
    const float* qr = q + (size_t)r * D_;
    const float* kb = k + (size_t)bh * N_ * D_;
    if (tid < D_) qd[tid] = (double)qr[tid];
    __syncthreads();
    double qsqd = 0.0;
    for (int d = 0; d < D_; ++d) qsqd = fma(qd[d], qd[d], qsqd);
    double bbest = 1e300;
    int bjj = 0;
    for (int j = tid; j <= i; j += 256) {
      const float* kr = kb + (size_t)j * D_;
      double a0 = 0, a1 = 0, s0 = 0, s1 = 0;
      for (int d = 0; d < D_; d += 2) {
        const double k0 = (double)kr[d], k1 = (double)kr[d + 1];
        a0 = fma(qd[d], k0, a0);  a1 = fma(qd[d + 1], k1, a1);
        s0 = fma(k0, k0, s0);     s1 = fma(k1, k1, s1);
      }
      const double raw = (qsqd + (s0 + s1)) - 2.0 * (a0 + a1);
      const double d2 = raw > 0.0 ? raw : 0.0;
      if (d2 < bbest) { bbest = d2; bjj = j; }   // ascending j -> first on tie
    }
    sd[tid] = bbest; sj[tid] = bjj;
    __syncthreads();
    for (int s = 128; s > 0; s >>= 1) {
      if (tid < s) {
        const double ob = sd[tid + s]; const int oj = sj[tid + s];
        if (ob < sd[tid] || (ob == sd[tid] && oj < sj[tid])) {
          sd[tid] = ob; sj[tid] = oj;
        }
      }
      __syncthreads();
    }
    const int jwin = sj[0];
    if (tid < 16) {
      const float4 val =
          ((const float4*)(v + ((size_t)bh * N_ + jwin) * D_))[tid];
      ((float4*)(out + (size_t)r * D_))[tid] = val;
    }
    __syncthreads();
  }
}

// ---------------------------------------------------------------------------
extern "C" void kernel_launch(void* const* d_in, const int* in_sizes, int n_in,
                              void* d_out, int out_size, void* d_ws,
                              size_t ws_size, hipStream_t stream) {
  const float* q = (const float*)d_in[0];
  const float* k = (const float*)d_in[1];
  const float* v = (const float*)d_in[2];
  float* out = (float*)d_out;

  // ws layout (256 MiB available):
  // [0: count][4K: flaglist 128K][256K: ksq 128K][1M: khi 4M][8M: klo 4M]
  // [16M: bestc 2M][24M: secc 1M]
  char* ws = (char*)d_ws;
  u32* count = (u32*)ws;
  u32* flaglist = (u32*)(ws + 4096);
  float* ksq_g = (float*)(ws + 256 * 1024);
  char* khi_g = ws + 1ull * 1024 * 1024;
  char* klo_g = ws + 8ull * 1024 * 1024;
  u64* bestc = (u64*)(ws + 16ull * 1024 * 1024);
  u32* secc = (u32*)(ws + 24ull * 1024 * 1024);

  prep_k<<<(NROWS * 8) / 256, 256, 0, stream>>>(k, khi_g, klo_g, ksq_g, count);
  phase1<<<NBLK1, 256, 0, stream>>>(q, khi_g, klo_g, ksq_g, bestc, secc);
  combine_gather<<<NROWS / 64, 256, 0, stream>>>(bestc, secc, v, out,
                                                 flaglist, count);
  exact_gather<<<64, 256, 0, stream>>>(q, k, v, out, flaglist, count);
}